// Round 13
// baseline (298.841 us; speedup 1.0000x reference)
//
#include <hip/hip_runtime.h>
#include <math.h>

#define FIN 128   // input features (layer1 K, layer2 K)
#define F1  128   // H1*C1 = layer1 output width
#define C2  64    // layer2 output width
#define NEG 0.2f  // leaky_relu negative slope

#define BKT_SHIFT 8
#define BKT_SIZE  256     // nodes per bucket
#define BKT_CAP   5120    // fixed slots per bucket (mean 4348, sigma 66 -> P(overflow)~1e-31)
#define SCAT_CHUNK 4096   // edges per block in scatter (LDS image)
#define IMGCAP 8192       // LDS csr-image capacity (ints) in build_csr

typedef _Float16 half4 __attribute__((ext_vector_type(4)));
typedef _Float16 f16x8 __attribute__((ext_vector_type(8)));
typedef _Float16 h2    __attribute__((ext_vector_type(2)));
typedef float    f32x4 __attribute__((ext_vector_type(4)));

union H8u { f16x8 v; h2 p[4]; };

#if __has_builtin(__builtin_amdgcn_fdot2)
__device__ __forceinline__ float fdot2_acc(h2 a, h2 b, float c) {
  return __builtin_amdgcn_fdot2(a, b, c, false);
}
#else
__device__ __forceinline__ float fdot2_acc(h2 a, h2 b, float c) {
  return c + (float)a[0] * (float)b[0] + (float)a[1] * (float)b[1];
}
#endif

// ================= bucketed CSR build (dst-grouped, fixed-capacity buckets) =================
__global__ __launch_bounds__(256) void bucket_scatter_kernel(
    const int* __restrict__ ei, int* __restrict__ bcur, int* __restrict__ tmp,
    int E, int ET, int NBKT) {
  __shared__ int sh_hist[512];
  __shared__ int sh_pref[512];
  __shared__ int sh_gbase[512];
  __shared__ int img[SCAT_CHUNK];
  __shared__ unsigned short bkt[SCAT_CHUNK];
  __shared__ int sh_tot;
  const int t = threadIdx.x;
  for (int b = t; b < NBKT; b += 256) sh_hist[b] = 0;
  if (t == 0) sh_tot = 0;
  __syncthreads();
  const int g0 = blockIdx.x * SCAT_CHUNK + t;
  int bk[16], pk[16];
#pragma unroll
  for (int i = 0; i < 16; ++i) {
    const int g = g0 + i * 256;
    int b = -1, p = 0;
    if (g < ET) {
      const int src = (g < E) ? ei[g] : (g - E);
      const int dst = (g < E) ? ei[E + g] : (g - E);
      b = dst >> BKT_SHIFT;
      p = (src << BKT_SHIFT) | (dst & (BKT_SIZE - 1));
      atomicAdd(&sh_hist[b], 1);
    }
    bk[i] = b; pk[i] = p;
  }
  __syncthreads();
  for (int b = t; b < NBKT; b += 256) {
    const int c = sh_hist[b];
    if (c) {
      sh_pref[b]  = atomicAdd(&sh_tot, c);
      sh_gbase[b] = b * BKT_CAP + atomicAdd(&bcur[b], c);
    }
    sh_hist[b] = 0;   // reuse as in-block cursor
  }
  __syncthreads();
#pragma unroll
  for (int i = 0; i < 16; ++i) {
    if (bk[i] >= 0) {
      const int slot = sh_pref[bk[i]] + atomicAdd(&sh_hist[bk[i]], 1);
      img[slot] = pk[i];
      bkt[slot] = (unsigned short)bk[i];
    }
  }
  __syncthreads();
  const int tot = sh_tot;
  for (int j = t; j < tot; j += 256) {
    const int b = bkt[j];
    tmp[sh_gbase[b] + (j - sh_pref[b])] = img[j];
  }
}

// Per-bucket: sort by dst-local (counting sort), emit per-node {beg,end} extents.
__global__ __launch_bounds__(256) void build_csr_kernel(
    const int* __restrict__ tmp, const int* __restrict__ bcnt,
    int2* __restrict__ ind2, int* __restrict__ csr, int N) {
  __shared__ int cnt[256];
  __shared__ int cur[256];
  __shared__ int img[IMGCAP];
  const int b = blockIdx.x;
  const int t = threadIdx.x;
  const int base = b * BKT_CAP;
  const int cntb = bcnt[b];
  cnt[t] = 0;
  __syncthreads();
  for (int i = t; i < cntb; i += 256)
    atomicAdd(&cnt[tmp[base + i] & (BKT_SIZE - 1)], 1);
  __syncthreads();
  const int v = cnt[t];
  cur[t] = v;
  __syncthreads();
  for (int off = 1; off < 256; off <<= 1) {
    int val = (t >= off) ? cur[t - off] : 0;
    __syncthreads();
    cur[t] += val;
    __syncthreads();
  }
  const int excl = cur[t] - v;
  const int node = (b << BKT_SHIFT) + t;
  if (node < N) ind2[node] = make_int2(base + excl, base + excl + v);
  __syncthreads();
  cur[t] = excl;
  __syncthreads();
  if (cntb <= IMGCAP) {
    for (int i = t; i < cntb; i += 256) {
      const int p = tmp[base + i];
      const int pos = atomicAdd(&cur[p & (BKT_SIZE - 1)], 1);
      img[pos] = p >> BKT_SHIFT;
    }
    __syncthreads();
    for (int i = t; i < cntb; i += 256) csr[base + i] = img[i];
  } else {
    for (int i = t; i < cntb; i += 256) {
      const int p = tmp[base + i];
      const int pos = atomicAdd(&cur[p & (BKT_SIZE - 1)], 1);
      csr[base + pos] = p >> BKT_SHIFT;
    }
  }
}

// ---------------- weight transpose+convert: Wt[n][128] = (fp16) W[k][n] ----------------
__global__ __launch_bounds__(256) void wtrans_kernel(
    const float* __restrict__ W0, const float* __restrict__ W1,
    const float* __restrict__ W2, const float* __restrict__ W3,
    _Float16* __restrict__ T0, _Float16* __restrict__ T1,
    _Float16* __restrict__ T2, _Float16* __restrict__ T3) {
  const int m = blockIdx.y;
  const float* W = (m == 0) ? W0 : (m == 1) ? W1 : (m == 2) ? W2 : W3;
  _Float16* T = (m == 0) ? T0 : (m == 1) ? T1 : (m == 2) ? T2 : T3;
  const int ncols = (m < 2) ? 128 : 64;
  const int idx = blockIdx.x * 256 + threadIdx.x;   // over ncols*128 (n,k)
  if (idx < ncols * 128) {
    const int n = idx >> 7;
    const int k = idx & 127;
    T[idx] = (_Float16)W[k * ncols + n];
  }
}

// ---------------- dual fp16 MFMA GEMM: {OL,OR} = A[M,128] @ {WL,WR}[128,NCOLS] + b ----------------
// A-tile staged through LDS once per block; coalesced loads; padded [16][136].
// AF32: A is fp32 (layer-1 input x), converted to f16 at stage time.
template<int NCOLS, int CPW, bool AF32>
__global__ __launch_bounds__(256) void gemm_dual_kernel(
    const void* __restrict__ Av,
    const _Float16* __restrict__ WtL, const float* __restrict__ bLp, _Float16* __restrict__ OL,
    const _Float16* __restrict__ WtR, const float* __restrict__ bRp, _Float16* __restrict__ ORp,
    int M) {
  __shared__ _Float16 lds[16 * 136];
  const int tid  = threadIdx.x;
  const int wave = tid >> 6;
  const int lane = tid & 63;
  const int row16 = lane & 15;
  const int quad  = lane >> 4;
  const int kb = quad * 8;
  f16x8 bfL[CPW][4], bfR[CPW][4];
  float bvL[CPW], bvR[CPW];
#pragma unroll
  for (int c = 0; c < CPW; ++c) {
    const int n0 = (wave * CPW + c) * 16;
    bvL[c] = bLp[n0 + row16];
    bvR[c] = bRp[n0 + row16];
#pragma unroll
    for (int kt = 0; kt < 4; ++kt) {
      bfL[c][kt] = *(const f16x8*)(WtL + (n0 + row16) * 128 + kt * 32 + kb);
      bfR[c][kt] = *(const f16x8*)(WtR + (n0 + row16) * 128 + kt * 32 + kb);
    }
  }
  const int rowTiles = (M + 15) >> 4;
  for (int rt = blockIdx.x; rt < rowTiles; rt += gridDim.x) {
    const int r0 = rt << 4;
    if constexpr (AF32) {
      const float4* x4 = (const float4*)Av;
#pragma unroll
      for (int i = 0; i < 2; ++i) {
        const int fi = i * 256 + tid;
        const int gr = fi >> 5;
        const int gc = fi & 31;
        const int row = min(r0 + gr, M - 1);
        const float4 u = x4[(size_t)row * 32 + gc];
        half4 h;
        h.x = (_Float16)u.x; h.y = (_Float16)u.y;
        h.z = (_Float16)u.z; h.w = (_Float16)u.w;
        *(half4*)(lds + gr * 136 + gc * 4) = h;
      }
    } else {
      const _Float16* A = (const _Float16*)Av;
      const int gr = tid >> 4;
      const int gc = tid & 15;
      const int row = min(r0 + gr, M - 1);
      *(f16x8*)(lds + gr * 136 + gc * 8) = *(const f16x8*)(A + (size_t)row * 128 + gc * 8);
    }
    __syncthreads();
    f16x8 af[4];
#pragma unroll
    for (int kt = 0; kt < 4; ++kt)
      af[kt] = *(const f16x8*)(lds + row16 * 136 + kt * 32 + kb);
    f32x4 accL[CPW], accR[CPW];
#pragma unroll
    for (int c = 0; c < CPW; ++c) {
      accL[c] = (f32x4){0.f, 0.f, 0.f, 0.f};
      accR[c] = (f32x4){0.f, 0.f, 0.f, 0.f};
    }
#pragma unroll
    for (int kt = 0; kt < 4; ++kt) {
#pragma unroll
      for (int c = 0; c < CPW; ++c) {
        accL[c] = __builtin_amdgcn_mfma_f32_16x16x32_f16(af[kt], bfL[c][kt], accL[c], 0, 0, 0);
        accR[c] = __builtin_amdgcn_mfma_f32_16x16x32_f16(af[kt], bfR[c][kt], accR[c], 0, 0, 0);
      }
    }
#pragma unroll
    for (int c = 0; c < CPW; ++c) {
      const int col = (wave * CPW + c) * 16 + row16;
#pragma unroll
      for (int r = 0; r < 4; ++r) {
        const int row = r0 + quad * 4 + r;
        if (row < M) {
          OL[(size_t)row * NCOLS + col]  = (_Float16)(accL[c][r] + bvL[c]);
          ORp[(size_t)row * NCOLS + col] = (_Float16)(accR[c][r] + bvR[c]);
        }
      }
    }
    __syncthreads();   // LDS reused next iteration
  }
}

// ---------------- attention batch: B gathers issued together, then compute ----------------
template<int LSH, int XORS, int B>
__device__ __forceinline__ void attn_block(const _Float16* __restrict__ xlp,
                                           const int* __restrict__ csr, int e,
                                           const H8u& xru, const H8u& atu,
                                           float& l, float (&acc)[8]) {
  const h2 neg2 = {(_Float16)NEG, (_Float16)NEG};
  int s[B];
#pragma unroll
  for (int i = 0; i < B; ++i) s[i] = csr[e + i];
  H8u x[B];
#pragma unroll
  for (int i = 0; i < B; ++i) x[i].v = *(const f16x8*)(xlp + ((size_t)s[i] << LSH));
  float t[B];
#pragma unroll
  for (int i = 0; i < B; ++i) {
    float tv = 0.f;
#pragma unroll
    for (int j = 0; j < 4; ++j) {
      h2 ev = x[i].p[j] + xru.p[j];
      ev = __builtin_elementwise_max(ev, ev * neg2);
      tv = fdot2_acc(ev, atu.p[j], tv);
    }
    t[i] = tv;
  }
#pragma unroll
  for (int i = 0; i < B; ++i) {
    t[i] += __shfl_xor(t[i], 1);
    if constexpr (XORS >= 2) t[i] += __shfl_xor(t[i], 2);
    if constexpr (XORS >= 3) t[i] += __shfl_xor(t[i], 4);
  }
  float p[B];
#pragma unroll
  for (int i = 0; i < B; ++i) { p[i] = __expf(t[i]); l += p[i]; }
#pragma unroll
  for (int i = 0; i < B; ++i) {
#pragma unroll
    for (int j = 0; j < 4; ++j) {
      acc[2*j]   = fmaf(p[i], (float)x[i].p[j][0], acc[2*j]);
      acc[2*j+1] = fmaf(p[i], (float)x[i].p[j][1], acc[2*j+1]);
    }
  }
}

template<int LSH, int XORS>
__device__ __forceinline__ void attn_edges(const _Float16* __restrict__ xlp,
                                           const int* __restrict__ csr,
                                           int beg, int end,
                                           const H8u& xru, const H8u& atu,
                                           float& l, float (&acc)[8]) {
  int e = beg;
  for (; e + 4 <= end; e += 4) attn_block<LSH, XORS, 4>(xlp, csr, e, xru, atu, l, acc);
  if (e + 2 <= end) { attn_block<LSH, XORS, 2>(xlp, csr, e, xru, atu, l, acc); e += 2; }
  if (e < end)      { attn_block<LSH, XORS, 1>(xlp, csr, e, xru, atu, l, acc); }
}

// ---------------- FUSED layer-1 attention + layer-2 transform ----------------
// Block = 16 nodes (N % 16 == 0 -> all blocks full, no early exit). After the attn epilogue,
// the block's 16 h-rows (ELU applied) are staged to LDS [16][136] and the 16x128 @ 128x64
// dual GEMM (gemm2) runs in-block: 8 MFMA, outputs xl2/xr2. Deletes the gemm2 dispatch and
// h's 25.6MB global write + 25.6MB re-read. No cross-block deps (tile = own nodes only).
__global__ __launch_bounds__(256) void attn1_fused_kernel(
    const _Float16* __restrict__ xl, const _Float16* __restrict__ xr,
    const float* __restrict__ att, const float* __restrict__ bias,
    const int2* __restrict__ ind2, const int* __restrict__ csr,
    const _Float16* __restrict__ Wt2l, const float* __restrict__ bl2, _Float16* __restrict__ OL,
    const _Float16* __restrict__ Wt2r, const float* __restrict__ br2, _Float16* __restrict__ ORp,
    int N) {
  __shared__ _Float16 hlds[16 * 136];
  const int tid = threadIdx.x;
  const int lane16 = tid & 15;
  const int nodeLoc = tid >> 4;
  const int v = blockIdx.x * 16 + nodeLoc;   // always < N (N % 16 == 0)
  const int c8 = lane16 << 3;
  const _Float16* xlp = xl + c8;
  H8u xru; xru.v = *(const f16x8*)(xr + ((size_t)v << 7) + c8);
  H8u atu;
  {
    const float4 a0 = *(const float4*)(att + c8);
    const float4 a1 = *(const float4*)(att + c8 + 4);
    f16x8 a;
    a[0] = (_Float16)a0.x; a[1] = (_Float16)a0.y; a[2] = (_Float16)a0.z; a[3] = (_Float16)a0.w;
    a[4] = (_Float16)a1.x; a[5] = (_Float16)a1.y; a[6] = (_Float16)a1.z; a[7] = (_Float16)a1.w;
    atu.v = a;
  }
  const int2 be = ind2[v];
  float l = 0.f;
  float acc[8] = {0.f, 0.f, 0.f, 0.f, 0.f, 0.f, 0.f, 0.f};
  attn_edges<7, 1>(xlp, csr, be.x, be.y, xru, atu, l, acc);

  const float rl = 1.f / l;
  const float4 bb0 = *(const float4*)(bias + c8);
  const float4 bb1 = *(const float4*)(bias + c8 + 4);
  float r[8];
  r[0] = fmaf(acc[0], rl, bb0.x); r[1] = fmaf(acc[1], rl, bb0.y);
  r[2] = fmaf(acc[2], rl, bb0.z); r[3] = fmaf(acc[3], rl, bb0.w);
  r[4] = fmaf(acc[4], rl, bb1.x); r[5] = fmaf(acc[5], rl, bb1.y);
  r[6] = fmaf(acc[6], rl, bb1.z); r[7] = fmaf(acc[7], rl, bb1.w);
  f16x8 hres;
#pragma unroll
  for (int i = 0; i < 8; ++i) {
    const float z = r[i] > 0.f ? r[i] : expm1f(r[i]);   // ELU
    hres[i] = (_Float16)z;
  }
  *(f16x8*)(hlds + nodeLoc * 136 + c8) = hres;   // h tile -> LDS (no global round-trip)
  __syncthreads();

  // ---- in-block gemm2: h[16][128] @ {Wt2l,Wt2r} -> xl2/xr2 [16][64] ----
  const int wave  = tid >> 6;
  const int lane  = tid & 63;
  const int row16 = lane & 15;
  const int quad  = lane >> 4;
  const int kb = quad * 8;
  const int n0 = wave * 16 + row16;   // output col 0..63
  const float bvL = bl2[n0];
  const float bvR = br2[n0];
  f16x8 af[4], bfL[4], bfR[4];
#pragma unroll
  for (int kt = 0; kt < 4; ++kt) {
    af[kt]  = *(const f16x8*)(hlds + row16 * 136 + kt * 32 + kb);
    bfL[kt] = *(const f16x8*)(Wt2l + n0 * 128 + kt * 32 + kb);
    bfR[kt] = *(const f16x8*)(Wt2r + n0 * 128 + kt * 32 + kb);
  }
  f32x4 accL = (f32x4){0.f, 0.f, 0.f, 0.f};
  f32x4 accR = (f32x4){0.f, 0.f, 0.f, 0.f};
#pragma unroll
  for (int kt = 0; kt < 4; ++kt) {
    accL = __builtin_amdgcn_mfma_f32_16x16x32_f16(af[kt], bfL[kt], accL, 0, 0, 0);
    accR = __builtin_amdgcn_mfma_f32_16x16x32_f16(af[kt], bfR[kt], accR, 0, 0, 0);
  }
  const int r0 = blockIdx.x * 16;
#pragma unroll
  for (int rr = 0; rr < 4; ++rr) {
    const int row = r0 + quad * 4 + rr;
    OL[(size_t)row * C2 + n0]  = (_Float16)(accL[rr] + bvL);
    ORp[(size_t)row * C2 + n0] = (_Float16)(accR[rr] + bvR);
  }
}

// ---------------- layer 2 fused attention: 8 lanes/node x 8 chans ----------------
__global__ __launch_bounds__(256) void attn2_kernel(
    const _Float16* __restrict__ xl, const _Float16* __restrict__ xr,
    const float* __restrict__ att, const float* __restrict__ bias,
    const int2* __restrict__ ind2, const int* __restrict__ csr,
    float* __restrict__ out, int N) {
  const int lane = threadIdx.x & 7;
  const int v = blockIdx.x * 32 + (threadIdx.x >> 3);
  if (v >= N) return;
  const int c8 = lane << 3;
  const _Float16* xlp = xl + c8;
  H8u xru; xru.v = *(const f16x8*)(xr + ((size_t)v << 6) + c8);
  H8u atu;
  {
    const float4 a0 = *(const float4*)(att + c8);
    const float4 a1 = *(const float4*)(att + c8 + 4);
    f16x8 a;
    a[0] = (_Float16)a0.x; a[1] = (_Float16)a0.y; a[2] = (_Float16)a0.z; a[3] = (_Float16)a0.w;
    a[4] = (_Float16)a1.x; a[5] = (_Float16)a1.y; a[6] = (_Float16)a1.z; a[7] = (_Float16)a1.w;
    atu.v = a;
  }
  const int2 be = ind2[v];
  const int beg = be.x;
  const int end = be.y;
  float l = 0.f;
  float acc[8] = {0.f, 0.f, 0.f, 0.f, 0.f, 0.f, 0.f, 0.f};
  attn_edges<6, 3>(xlp, csr, beg, end, xru, atu, l, acc);

  const float rl = 1.f / l;
  const float4 bb0 = *(const float4*)(bias + c8);
  const float4 bb1 = *(const float4*)(bias + c8 + 4);
  float4 o0, o1;
  o0.x = fmaf(acc[0], rl, bb0.x); o0.y = fmaf(acc[1], rl, bb0.y);
  o0.z = fmaf(acc[2], rl, bb0.z); o0.w = fmaf(acc[3], rl, bb0.w);
  o1.x = fmaf(acc[4], rl, bb1.x); o1.y = fmaf(acc[5], rl, bb1.y);
  o1.z = fmaf(acc[6], rl, bb1.z); o1.w = fmaf(acc[7], rl, bb1.w);
  *(float4*)(out + ((size_t)v << 6) + c8) = o0;
  *(float4*)(out + ((size_t)v << 6) + c8 + 4) = o1;
}

extern "C" void kernel_launch(void* const* d_in, const int* in_sizes, int n_in,
                              void* d_out, int out_size, void* d_ws, size_t ws_size,
                              hipStream_t stream) {
  const float* x     = (const float*)d_in[0];
  const int*   ei    = (const int*)d_in[1];
  const float* Wl1   = (const float*)d_in[2];
  const float* bl1   = (const float*)d_in[3];
  const float* Wr1   = (const float*)d_in[4];
  const float* br1   = (const float*)d_in[5];
  const float* att1  = (const float*)d_in[6];
  const float* bias1 = (const float*)d_in[7];
  const float* Wl2   = (const float*)d_in[8];
  const float* bl2   = (const float*)d_in[9];
  const float* Wr2   = (const float*)d_in[10];
  const float* br2   = (const float*)d_in[11];
  const float* att2  = (const float*)d_in[12];
  const float* bias2 = (const float*)d_in[13];

  const int N  = in_sizes[0] / FIN;   // 100000 (divisible by 16)
  const int E  = in_sizes[1] / 2;     // 1600000
  const int ET = E + N;
  const int NBKT = (N + BKT_SIZE - 1) >> BKT_SHIFT;   // 391 (<=512 required)

  // workspace layout
  _Float16* xl1h  = (_Float16*)d_ws;                   // N*128 f16
  _Float16* xr1h  = xl1h + (size_t)N * F1;             // N*128 f16
  _Float16* hregion = xr1h + (size_t)N * F1;           // N*128 f16 region (now holds xl2+xr2)
  _Float16* Wt1l  = hregion + (size_t)N * F1;          // 128*128 f16
  _Float16* Wt1r  = Wt1l + 128 * 128;
  _Float16* Wt2l  = Wt1r + 128 * 128;                  // 64*128 f16
  _Float16* Wt2r  = Wt2l + 64 * 128;
  int2* ind2  = (int2*)(Wt2r + 64 * 128);              // N int2
  int* csr    = (int*)(ind2 + N);                      // NBKT*BKT_CAP (padded)
  int* bcur   = csr + (size_t)NBKT * BKT_CAP;          // 512
  int* tmp    = (int*)hregion;  // alias: dead before attn1_fused writes xl2/xr2
  _Float16* xl2h = hregion;                            // N*64 f16
  _Float16* xr2h = hregion + (size_t)N * C2;           // N*64 f16
  float* out  = (float*)d_out;

  const int sblocks = (ET + SCAT_CHUNK - 1) / SCAT_CHUNK;   // 416

  hipMemsetAsync(bcur, 0, 512 * sizeof(int), stream);
  bucket_scatter_kernel<<<sblocks, 256, 0, stream>>>(ei, bcur, tmp, E, ET, NBKT);
  build_csr_kernel<<<NBKT, 256, 0, stream>>>(tmp, bcur, ind2, csr, N);

  wtrans_kernel<<<dim3(64, 4), 256, 0, stream>>>(Wl1, Wr1, Wl2, Wr2, Wt1l, Wt1r, Wt2l, Wt2r);

  // layer-1 transform: LDS-staged A, coalesced loads
  gemm_dual_kernel<128, 2, true><<<1024, 256, 0, stream>>>(
      x, Wt1l, bl1, xl1h, Wt1r, br1, xr1h, N);

  // fused layer-1 attention + layer-2 transform (gemm2 dispatch + h round-trip deleted)
  attn1_fused_kernel<<<N / 16, 256, 0, stream>>>(
      xl1h, xr1h, att1, bias1, ind2, csr,
      Wt2l, bl2, xl2h, Wt2r, br2, xr2h, N);

  attn2_kernel<<<(N + 31) / 32, 256, 0, stream>>>(xl2h, xr2h, att2, bias2, ind2, csr, out, N);
}

// Round 14
// 293.968 us; speedup vs baseline: 1.0166x; 1.0166x over previous
//
#include <hip/hip_runtime.h>
#include <math.h>

#define FIN 128   // input features (layer1 K, layer2 K)
#define F1  128   // H1*C1 = layer1 output width
#define C2  64    // layer2 output width
#define NEG 0.2f  // leaky_relu negative slope

#define BKT_SHIFT 8
#define BKT_SIZE  256     // nodes per bucket
#define BKT_CAP   5120    // fixed slots per bucket (mean 4348, sigma 66 -> P(overflow)~1e-31)
#define SCAT_CHUNK 4096   // edges per block in scatter (LDS image)
#define IMGCAP 8192       // LDS csr-image capacity (ints) in build_csr

typedef _Float16 half4 __attribute__((ext_vector_type(4)));
typedef _Float16 f16x8 __attribute__((ext_vector_type(8)));
typedef _Float16 h2    __attribute__((ext_vector_type(2)));
typedef float    f32x4 __attribute__((ext_vector_type(4)));

union H8u { f16x8 v; h2 p[4]; };

#if __has_builtin(__builtin_amdgcn_fdot2)
__device__ __forceinline__ float fdot2_acc(h2 a, h2 b, float c) {
  return __builtin_amdgcn_fdot2(a, b, c, false);
}
#else
__device__ __forceinline__ float fdot2_acc(h2 a, h2 b, float c) {
  return c + (float)a[0] * (float)b[0] + (float)a[1] * (float)b[1];
}
#endif

// ================= bucketed CSR build (dst-grouped, fixed-capacity buckets) =================
__global__ __launch_bounds__(256) void bucket_scatter_kernel(
    const int* __restrict__ ei, int* __restrict__ bcur, int* __restrict__ tmp,
    int E, int ET, int NBKT) {
  __shared__ int sh_hist[512];
  __shared__ int sh_pref[512];
  __shared__ int sh_gbase[512];
  __shared__ int img[SCAT_CHUNK];
  __shared__ unsigned short bkt[SCAT_CHUNK];
  __shared__ int sh_tot;
  const int t = threadIdx.x;
  for (int b = t; b < NBKT; b += 256) sh_hist[b] = 0;
  if (t == 0) sh_tot = 0;
  __syncthreads();
  const int g0 = blockIdx.x * SCAT_CHUNK + t;
  int bk[16], pk[16];
#pragma unroll
  for (int i = 0; i < 16; ++i) {
    const int g = g0 + i * 256;
    int b = -1, p = 0;
    if (g < ET) {
      const int src = (g < E) ? ei[g] : (g - E);
      const int dst = (g < E) ? ei[E + g] : (g - E);
      b = dst >> BKT_SHIFT;
      p = (src << BKT_SHIFT) | (dst & (BKT_SIZE - 1));
      atomicAdd(&sh_hist[b], 1);
    }
    bk[i] = b; pk[i] = p;
  }
  __syncthreads();
  for (int b = t; b < NBKT; b += 256) {
    const int c = sh_hist[b];
    if (c) {
      sh_pref[b]  = atomicAdd(&sh_tot, c);
      sh_gbase[b] = b * BKT_CAP + atomicAdd(&bcur[b], c);
    }
    sh_hist[b] = 0;   // reuse as in-block cursor
  }
  __syncthreads();
#pragma unroll
  for (int i = 0; i < 16; ++i) {
    if (bk[i] >= 0) {
      const int slot = sh_pref[bk[i]] + atomicAdd(&sh_hist[bk[i]], 1);
      img[slot] = pk[i];
      bkt[slot] = (unsigned short)bk[i];
    }
  }
  __syncthreads();
  const int tot = sh_tot;
  for (int j = t; j < tot; j += 256) {
    const int b = bkt[j];
    tmp[sh_gbase[b] + (j - sh_pref[b])] = img[j];
  }
}

// Per-bucket: sort by dst-local (counting sort), emit per-node {beg,end} extents.
__global__ __launch_bounds__(256) void build_csr_kernel(
    const int* __restrict__ tmp, const int* __restrict__ bcnt,
    int2* __restrict__ ind2, int* __restrict__ csr, int N) {
  __shared__ int cnt[256];
  __shared__ int cur[256];
  __shared__ int img[IMGCAP];
  const int b = blockIdx.x;
  const int t = threadIdx.x;
  const int base = b * BKT_CAP;
  const int cntb = bcnt[b];
  cnt[t] = 0;
  __syncthreads();
  for (int i = t; i < cntb; i += 256)
    atomicAdd(&cnt[tmp[base + i] & (BKT_SIZE - 1)], 1);
  __syncthreads();
  const int v = cnt[t];
  cur[t] = v;
  __syncthreads();
  for (int off = 1; off < 256; off <<= 1) {
    int val = (t >= off) ? cur[t - off] : 0;
    __syncthreads();
    cur[t] += val;
    __syncthreads();
  }
  const int excl = cur[t] - v;
  const int node = (b << BKT_SHIFT) + t;
  if (node < N) ind2[node] = make_int2(base + excl, base + excl + v);
  __syncthreads();
  cur[t] = excl;
  __syncthreads();
  if (cntb <= IMGCAP) {
    for (int i = t; i < cntb; i += 256) {
      const int p = tmp[base + i];
      const int pos = atomicAdd(&cur[p & (BKT_SIZE - 1)], 1);
      img[pos] = p >> BKT_SHIFT;
    }
    __syncthreads();
    for (int i = t; i < cntb; i += 256) csr[base + i] = img[i];
  } else {
    for (int i = t; i < cntb; i += 256) {
      const int p = tmp[base + i];
      const int pos = atomicAdd(&cur[p & (BKT_SIZE - 1)], 1);
      csr[base + pos] = p >> BKT_SHIFT;
    }
  }
}

// ---------------- weight transpose+convert + bcur zeroing (fused; R6-proven pattern) ----------
__global__ __launch_bounds__(256) void wtrans_kernel(
    const float* __restrict__ W0, const float* __restrict__ W1,
    const float* __restrict__ W2, const float* __restrict__ W3,
    _Float16* __restrict__ T0, _Float16* __restrict__ T1,
    _Float16* __restrict__ T2, _Float16* __restrict__ T3,
    int* __restrict__ bcur) {
  const int m = blockIdx.y;
  if (m == 0 && blockIdx.x == 0) {
    bcur[threadIdx.x] = 0;
    bcur[threadIdx.x + 256] = 0;
  }
  const float* W = (m == 0) ? W0 : (m == 1) ? W1 : (m == 2) ? W2 : W3;
  _Float16* T = (m == 0) ? T0 : (m == 1) ? T1 : (m == 2) ? T2 : T3;
  const int ncols = (m < 2) ? 128 : 64;
  const int idx = blockIdx.x * 256 + threadIdx.x;   // over ncols*128 (n,k)
  if (idx < ncols * 128) {
    const int n = idx >> 7;
    const int k = idx & 127;
    T[idx] = (_Float16)W[k * ncols + n];
  }
}

// ---------------- dual fp16 MFMA GEMM: {OL,OR} = A[M,128] @ {WL,WR}[128,NCOLS] + b ----------------
// A-tile staged through LDS once per block; coalesced loads; padded [16][136]. (R12-verified)
// AF32: A is fp32 (layer-1 input x), converted to f16 at stage time.
template<int NCOLS, int CPW, bool AF32>
__global__ __launch_bounds__(256) void gemm_dual_kernel(
    const void* __restrict__ Av,
    const _Float16* __restrict__ WtL, const float* __restrict__ bLp, _Float16* __restrict__ OL,
    const _Float16* __restrict__ WtR, const float* __restrict__ bRp, _Float16* __restrict__ ORp,
    int M) {
  __shared__ _Float16 lds[16 * 136];
  const int tid  = threadIdx.x;
  const int wave = tid >> 6;
  const int lane = tid & 63;
  const int row16 = lane & 15;
  const int quad  = lane >> 4;
  const int kb = quad * 8;
  f16x8 bfL[CPW][4], bfR[CPW][4];
  float bvL[CPW], bvR[CPW];
#pragma unroll
  for (int c = 0; c < CPW; ++c) {
    const int n0 = (wave * CPW + c) * 16;
    bvL[c] = bLp[n0 + row16];
    bvR[c] = bRp[n0 + row16];
#pragma unroll
    for (int kt = 0; kt < 4; ++kt) {
      bfL[c][kt] = *(const f16x8*)(WtL + (n0 + row16) * 128 + kt * 32 + kb);
      bfR[c][kt] = *(const f16x8*)(WtR + (n0 + row16) * 128 + kt * 32 + kb);
    }
  }
  const int rowTiles = (M + 15) >> 4;
  for (int rt = blockIdx.x; rt < rowTiles; rt += gridDim.x) {
    const int r0 = rt << 4;
    if constexpr (AF32) {
      const float4* x4 = (const float4*)Av;
#pragma unroll
      for (int i = 0; i < 2; ++i) {
        const int fi = i * 256 + tid;
        const int gr = fi >> 5;
        const int gc = fi & 31;
        const int row = min(r0 + gr, M - 1);
        const float4 u = x4[(size_t)row * 32 + gc];
        half4 h;
        h.x = (_Float16)u.x; h.y = (_Float16)u.y;
        h.z = (_Float16)u.z; h.w = (_Float16)u.w;
        *(half4*)(lds + gr * 136 + gc * 4) = h;
      }
    } else {
      const _Float16* A = (const _Float16*)Av;
      const int gr = tid >> 4;
      const int gc = tid & 15;
      const int row = min(r0 + gr, M - 1);
      *(f16x8*)(lds + gr * 136 + gc * 8) = *(const f16x8*)(A + (size_t)row * 128 + gc * 8);
    }
    __syncthreads();
    f16x8 af[4];
#pragma unroll
    for (int kt = 0; kt < 4; ++kt)
      af[kt] = *(const f16x8*)(lds + row16 * 136 + kt * 32 + kb);
    f32x4 accL[CPW], accR[CPW];
#pragma unroll
    for (int c = 0; c < CPW; ++c) {
      accL[c] = (f32x4){0.f, 0.f, 0.f, 0.f};
      accR[c] = (f32x4){0.f, 0.f, 0.f, 0.f};
    }
#pragma unroll
    for (int kt = 0; kt < 4; ++kt) {
#pragma unroll
      for (int c = 0; c < CPW; ++c) {
        accL[c] = __builtin_amdgcn_mfma_f32_16x16x32_f16(af[kt], bfL[c][kt], accL[c], 0, 0, 0);
        accR[c] = __builtin_amdgcn_mfma_f32_16x16x32_f16(af[kt], bfR[c][kt], accR[c], 0, 0, 0);
      }
    }
#pragma unroll
    for (int c = 0; c < CPW; ++c) {
      const int col = (wave * CPW + c) * 16 + row16;
#pragma unroll
      for (int r = 0; r < 4; ++r) {
        const int row = r0 + quad * 4 + r;
        if (row < M) {
          OL[(size_t)row * NCOLS + col]  = (_Float16)(accL[c][r] + bvL[c]);
          ORp[(size_t)row * NCOLS + col] = (_Float16)(accR[c][r] + bvR[c]);
        }
      }
    }
    __syncthreads();   // LDS reused next iteration
  }
}

// ---------------- attention batch: B gathers issued together, then compute ----------------
template<int LSH, int XORS, int B>
__device__ __forceinline__ void attn_block(const _Float16* __restrict__ xlp,
                                           const int* __restrict__ csr, int e,
                                           const H8u& xru, const H8u& atu,
                                           float& l, float (&acc)[8]) {
  const h2 neg2 = {(_Float16)NEG, (_Float16)NEG};
  int s[B];
#pragma unroll
  for (int i = 0; i < B; ++i) s[i] = csr[e + i];
  H8u x[B];
#pragma unroll
  for (int i = 0; i < B; ++i) x[i].v = *(const f16x8*)(xlp + ((size_t)s[i] << LSH));
  float t[B];
#pragma unroll
  for (int i = 0; i < B; ++i) {
    float tv = 0.f;
#pragma unroll
    for (int j = 0; j < 4; ++j) {
      h2 ev = x[i].p[j] + xru.p[j];
      ev = __builtin_elementwise_max(ev, ev * neg2);
      tv = fdot2_acc(ev, atu.p[j], tv);
    }
    t[i] = tv;
  }
#pragma unroll
  for (int i = 0; i < B; ++i) {
    t[i] += __shfl_xor(t[i], 1);
    if constexpr (XORS >= 2) t[i] += __shfl_xor(t[i], 2);
    if constexpr (XORS >= 3) t[i] += __shfl_xor(t[i], 4);
  }
  float p[B];
#pragma unroll
  for (int i = 0; i < B; ++i) { p[i] = __expf(t[i]); l += p[i]; }
#pragma unroll
  for (int i = 0; i < B; ++i) {
#pragma unroll
    for (int j = 0; j < 4; ++j) {
      acc[2*j]   = fmaf(p[i], (float)x[i].p[j][0], acc[2*j]);
      acc[2*j+1] = fmaf(p[i], (float)x[i].p[j][1], acc[2*j+1]);
    }
  }
}

template<int LSH, int XORS>
__device__ __forceinline__ void attn_edges(const _Float16* __restrict__ xlp,
                                           const int* __restrict__ csr,
                                           int beg, int end,
                                           const H8u& xru, const H8u& atu,
                                           float& l, float (&acc)[8]) {
  int e = beg;
  for (; e + 4 <= end; e += 4) attn_block<LSH, XORS, 4>(xlp, csr, e, xru, atu, l, acc);
  if (e + 2 <= end) { attn_block<LSH, XORS, 2>(xlp, csr, e, xru, atu, l, acc); e += 2; }
  if (e < end)      { attn_block<LSH, XORS, 1>(xlp, csr, e, xru, atu, l, acc); }
}

// ---------------- layer 1 fused attention: 16 lanes/node x 8 chans ----------------
// (R12 form — unfused; R13's in-block gemm2 fusion regressed: block-max degree sync cost
//  ~20us > gemm2's ~15us. Keep attention waves independently-retiring.)
__global__ __launch_bounds__(256) void attn1_kernel(
    const _Float16* __restrict__ xl, const _Float16* __restrict__ xr,
    const float* __restrict__ att, const float* __restrict__ bias,
    const int2* __restrict__ ind2, const int* __restrict__ csr,
    _Float16* __restrict__ hout, int N) {
  const int lane = threadIdx.x & 15;
  const int v = blockIdx.x * 16 + (threadIdx.x >> 4);
  if (v >= N) return;
  const int c8 = lane << 3;
  const _Float16* xlp = xl + c8;
  H8u xru; xru.v = *(const f16x8*)(xr + ((size_t)v << 7) + c8);
  H8u atu;
  {
    const float4 a0 = *(const float4*)(att + c8);
    const float4 a1 = *(const float4*)(att + c8 + 4);
    f16x8 a;
    a[0] = (_Float16)a0.x; a[1] = (_Float16)a0.y; a[2] = (_Float16)a0.z; a[3] = (_Float16)a0.w;
    a[4] = (_Float16)a1.x; a[5] = (_Float16)a1.y; a[6] = (_Float16)a1.z; a[7] = (_Float16)a1.w;
    atu.v = a;
  }
  const int2 be = ind2[v];
  const int beg = be.x;
  const int end = be.y;
  float l = 0.f;
  float acc[8] = {0.f, 0.f, 0.f, 0.f, 0.f, 0.f, 0.f, 0.f};
  attn_edges<7, 1>(xlp, csr, beg, end, xru, atu, l, acc);

  const float rl = 1.f / l;
  const float4 bb0 = *(const float4*)(bias + c8);
  const float4 bb1 = *(const float4*)(bias + c8 + 4);
  float r[8];
  r[0] = fmaf(acc[0], rl, bb0.x); r[1] = fmaf(acc[1], rl, bb0.y);
  r[2] = fmaf(acc[2], rl, bb0.z); r[3] = fmaf(acc[3], rl, bb0.w);
  r[4] = fmaf(acc[4], rl, bb1.x); r[5] = fmaf(acc[5], rl, bb1.y);
  r[6] = fmaf(acc[6], rl, bb1.z); r[7] = fmaf(acc[7], rl, bb1.w);
  f16x8 hres;
#pragma unroll
  for (int i = 0; i < 8; ++i) {
    const float z = r[i] > 0.f ? r[i] : expm1f(r[i]);   // ELU
    hres[i] = (_Float16)z;
  }
  *(f16x8*)(hout + ((size_t)v << 7) + c8) = hres;
}

// ---------------- layer 2 fused attention: 8 lanes/node x 8 chans ----------------
__global__ __launch_bounds__(256) void attn2_kernel(
    const _Float16* __restrict__ xl, const _Float16* __restrict__ xr,
    const float* __restrict__ att, const float* __restrict__ bias,
    const int2* __restrict__ ind2, const int* __restrict__ csr,
    float* __restrict__ out, int N) {
  const int lane = threadIdx.x & 7;
  const int v = blockIdx.x * 32 + (threadIdx.x >> 3);
  if (v >= N) return;
  const int c8 = lane << 3;
  const _Float16* xlp = xl + c8;
  H8u xru; xru.v = *(const f16x8*)(xr + ((size_t)v << 6) + c8);
  H8u atu;
  {
    const float4 a0 = *(const float4*)(att + c8);
    const float4 a1 = *(const float4*)(att + c8 + 4);
    f16x8 a;
    a[0] = (_Float16)a0.x; a[1] = (_Float16)a0.y; a[2] = (_Float16)a0.z; a[3] = (_Float16)a0.w;
    a[4] = (_Float16)a1.x; a[5] = (_Float16)a1.y; a[6] = (_Float16)a1.z; a[7] = (_Float16)a1.w;
    atu.v = a;
  }
  const int2 be = ind2[v];
  const int beg = be.x;
  const int end = be.y;
  float l = 0.f;
  float acc[8] = {0.f, 0.f, 0.f, 0.f, 0.f, 0.f, 0.f, 0.f};
  attn_edges<6, 3>(xlp, csr, beg, end, xru, atu, l, acc);

  const float rl = 1.f / l;
  const float4 bb0 = *(const float4*)(bias + c8);
  const float4 bb1 = *(const float4*)(bias + c8 + 4);
  float4 o0, o1;
  o0.x = fmaf(acc[0], rl, bb0.x); o0.y = fmaf(acc[1], rl, bb0.y);
  o0.z = fmaf(acc[2], rl, bb0.z); o0.w = fmaf(acc[3], rl, bb0.w);
  o1.x = fmaf(acc[4], rl, bb1.x); o1.y = fmaf(acc[5], rl, bb1.y);
  o1.z = fmaf(acc[6], rl, bb1.z); o1.w = fmaf(acc[7], rl, bb1.w);
  *(float4*)(out + ((size_t)v << 6) + c8) = o0;
  *(float4*)(out + ((size_t)v << 6) + c8 + 4) = o1;
}

extern "C" void kernel_launch(void* const* d_in, const int* in_sizes, int n_in,
                              void* d_out, int out_size, void* d_ws, size_t ws_size,
                              hipStream_t stream) {
  const float* x     = (const float*)d_in[0];
  const int*   ei    = (const int*)d_in[1];
  const float* Wl1   = (const float*)d_in[2];
  const float* bl1   = (const float*)d_in[3];
  const float* Wr1   = (const float*)d_in[4];
  const float* br1   = (const float*)d_in[5];
  const float* att1  = (const float*)d_in[6];
  const float* bias1 = (const float*)d_in[7];
  const float* Wl2   = (const float*)d_in[8];
  const float* bl2   = (const float*)d_in[9];
  const float* Wr2   = (const float*)d_in[10];
  const float* br2   = (const float*)d_in[11];
  const float* att2  = (const float*)d_in[12];
  const float* bias2 = (const float*)d_in[13];

  const int N  = in_sizes[0] / FIN;   // 100000
  const int E  = in_sizes[1] / 2;     // 1600000
  const int ET = E + N;
  const int NBKT = (N + BKT_SIZE - 1) >> BKT_SHIFT;   // 391 (<=512 required)

  // workspace layout (R12)
  _Float16* xl1h  = (_Float16*)d_ws;                   // N*128 f16
  _Float16* xr1h  = xl1h + (size_t)N * F1;             // N*128 f16
  _Float16* hbufh = xr1h + (size_t)N * F1;             // N*128 f16
  _Float16* Wt1l  = hbufh + (size_t)N * F1;            // 128*128 f16
  _Float16* Wt1r  = Wt1l + 128 * 128;
  _Float16* Wt2l  = Wt1r + 128 * 128;                  // 64*128 f16
  _Float16* Wt2r  = Wt2l + 64 * 128;
  int2* ind2  = (int2*)(Wt2r + 64 * 128);              // N int2
  int* csr    = (int*)(ind2 + N);                      // NBKT*BKT_CAP (padded)
  int* bcur   = csr + (size_t)NBKT * BKT_CAP;          // 512
  int* tmp    = (int*)hbufh;   // alias: NBKT*BKT_CAP ints (8MB) < N*128 f16 (25.6MB); dead before attn1 writes hbufh
  _Float16* xl2h = xl1h;                               // reuse after attn1
  _Float16* xr2h = xr1h;
  float* out  = (float*)d_out;

  const int sblocks = (ET + SCAT_CHUNK - 1) / SCAT_CHUNK;   // 416

  // wtrans first: also zeroes bcur (replaces hipMemsetAsync dispatch)
  wtrans_kernel<<<dim3(64, 4), 256, 0, stream>>>(
      Wl1, Wr1, Wl2, Wr2, Wt1l, Wt1r, Wt2l, Wt2r, bcur);

  bucket_scatter_kernel<<<sblocks, 256, 0, stream>>>(ei, bcur, tmp, E, ET, NBKT);
  build_csr_kernel<<<NBKT, 256, 0, stream>>>(tmp, bcur, ind2, csr, N);

  // layer-1 transform: LDS-staged A, coalesced loads
  gemm_dual_kernel<128, 2, true><<<1024, 256, 0, stream>>>(
      x, Wt1l, bl1, xl1h, Wt1r, br1, xr1h, N);

  attn1_kernel<<<(N + 15) / 16, 256, 0, stream>>>(xl1h, xr1h, att1, bias1, ind2, csr, hbufh, N);

  // layer-2 transform: LDS-staged A
  gemm_dual_kernel<64, 1, false><<<1024, 256, 0, stream>>>(
      hbufh, Wt2l, bl2, xl2h, Wt2r, br2, xr2h, N);

  attn2_kernel<<<(N + 31) / 32, 256, 0, stream>>>(xl2h, xr2h, att2, bias2, ind2, csr, out, N);
}